// Round 2
// baseline (6764.983 us; speedup 1.0000x reference)
//
#include <hip/hip_runtime.h>
#include <cstddef>

#define S_LEN 256
#define H_DIM 512
#define G_DIM 2048
#define B_SZ  4
#define V_SZ  32000

__device__ __forceinline__ float sigf(float x) { return 1.0f / (1.0f + expf(-x)); }

// ---------------- zero init ----------------
__global__ void zero_kernel(float* __restrict__ p, int n4) {
  int i = blockIdx.x * blockDim.x + threadIdx.x;
  if (i < n4) ((float4*)p)[i] = make_float4(0.f, 0.f, 0.f, 0.f);
}

// ---------------- embedding + DyT ----------------
__global__ __launch_bounds__(128)
void embed_dyt(const int* __restrict__ idx, const float* __restrict__ E,
               const float* __restrict__ alpha_p, const float* __restrict__ gamma,
               const float* __restrict__ beta, float* __restrict__ out) {
  const int row = blockIdx.x;          // b*S + s
  const int t4  = threadIdx.x * 4;     // 0..508
  const int id  = idx[row];
  const float al = alpha_p[0];
  float4 e = make_float4(0.f, 0.f, 0.f, 0.f);
  if (id != 0) e = *(const float4*)(E + (size_t)id * H_DIM + t4);
  const float4 g = *(const float4*)(gamma + t4);
  const float4 b = *(const float4*)(beta + t4);
  float4 o;
  o.x = g.x * tanhf(al * e.x) + b.x;
  o.y = g.y * tanhf(al * e.y) + b.y;
  o.z = g.z * tanhf(al * e.z) + b.z;
  o.w = g.w * tanhf(al * e.w) + b.w;
  *(float4*)(out + (size_t)row * H_DIM + t4) = o;
}

// ---------------- GEMM: C[M,N] = A[M,K] @ W[N,K]^T + bias, optional DyT epilogue ----
template<int EPI>
__global__ __launch_bounds__(256)
void gemm_nt(const float* __restrict__ A, const float* __restrict__ W,
             const float* __restrict__ bias, float* __restrict__ C,
             int N, int K,
             const float* __restrict__ alpha_p, const float* __restrict__ gamma,
             const float* __restrict__ beta, const float* __restrict__ residual) {
  __shared__ float As[8][132];
  __shared__ float Ws[8][132];
  const int bm = blockIdx.x * 128;
  const int bn = blockIdx.y * 128;
  const int tid = threadIdx.x;
  const int tx = tid & 15, ty = tid >> 4;
  float acc[8][8] = {};
  const int i4 = tid * 4;
  const int lm = i4 >> 3;
  const int lk = i4 & 7;
  const float* Arow = A + (size_t)(bm + lm) * K + lk;
  const float* Wrow = W + (size_t)(bn + lm) * K + lk;

  for (int k0 = 0; k0 < K; k0 += 8) {
    float4 va = *(const float4*)(Arow + k0);
    float4 vw = *(const float4*)(Wrow + k0);
    As[lk + 0][lm] = va.x; As[lk + 1][lm] = va.y; As[lk + 2][lm] = va.z; As[lk + 3][lm] = va.w;
    Ws[lk + 0][lm] = vw.x; Ws[lk + 1][lm] = vw.y; Ws[lk + 2][lm] = vw.z; Ws[lk + 3][lm] = vw.w;
    __syncthreads();
#pragma unroll
    for (int kk = 0; kk < 8; ++kk) {
      float a[8], w[8];
      *(float4*)(a)     = *(const float4*)&As[kk][ty * 4];
      *(float4*)(a + 4) = *(const float4*)&As[kk][64 + ty * 4];
      *(float4*)(w)     = *(const float4*)&Ws[kk][tx * 4];
      *(float4*)(w + 4) = *(const float4*)&Ws[kk][64 + tx * 4];
#pragma unroll
      for (int ii = 0; ii < 8; ++ii)
#pragma unroll
        for (int jj = 0; jj < 8; ++jj)
          acc[ii][jj] += a[ii] * w[jj];
    }
    __syncthreads();
  }

  float al = 0.f;
  if (EPI == 1) al = alpha_p[0];
#pragma unroll
  for (int ii = 0; ii < 8; ++ii) {
    const int row = bm + ((ii < 4) ? (ty * 4 + ii) : (60 + ty * 4 + ii));
#pragma unroll
    for (int hf = 0; hf < 2; ++hf) {
      const int ncol = bn + hf * 64 + tx * 4;
      float4 v;
      v.x = acc[ii][hf * 4 + 0]; v.y = acc[ii][hf * 4 + 1];
      v.z = acc[ii][hf * 4 + 2]; v.w = acc[ii][hf * 4 + 3];
      const float4 bb = *(const float4*)(bias + ncol);
      v.x += bb.x; v.y += bb.y; v.z += bb.z; v.w += bb.w;
      if (EPI == 1) {
        if (residual) {
          const float4 r = *(const float4*)(residual + (size_t)row * N + ncol);
          v.x += r.x; v.y += r.y; v.z += r.z; v.w += r.w;
        }
        const float4 gg = *(const float4*)(gamma + ncol);
        const float4 be = *(const float4*)(beta + ncol);
        v.x = gg.x * tanhf(al * v.x) + be.x;
        v.y = gg.y * tanhf(al * v.y) + be.y;
        v.z = gg.z * tanhf(al * v.z) + be.z;
        v.w = gg.w * tanhf(al * v.w) + be.w;
      }
      *(float4*)(C + (size_t)row * N + ncol) = v;
    }
  }
}

// ---------------- persistent SLSTM phase ----------------
struct PhaseArgs {
  const float* xg;       // [(b*S+t)*stride + grow]
  const float* Whh;      // [2048,512]
  const float* bhh;      // [2048]
  const float* c_init;   // [4,512]
  const float* h_init;   // [4,512]
  float* c_fin;          // [4,512] or nullptr
  float* hbuf;           // ring [2][4*512]
  int*   flags;          // [64]
  float* spk;            // [B*S,512] or nullptr
  const float* thr;      // [512]
  int xg_stride;
  int nsteps;
};

// grid: 64 WGs per instance, 256 threads. WG g owns h columns [8g, 8g+8).
__global__ __launch_bounds__(256)
void slstm_persist(PhaseArgs A0, PhaseArgs A1) {
  const PhaseArgs P = (blockIdx.x < 64) ? A0 : A1;
  const int g = blockIdx.x & 63;
  const int tid = threadIdx.x;
  const int lr = tid >> 3, kc = tid & 7;   // 32 rows x 8 k-chunks
  const int q = lr >> 3, ci = lr & 7;      // gate q, local col ci
  const int col0 = g * 8;
  const int grow = q * H_DIM + col0 + ci;

  // ---- weights resident in VGPRs: 16 x float4 = 64 floats per thread ----
  float4 w[16];
  {
    const float* wrow = P.Whh + (size_t)grow * H_DIM + kc * 4;
#pragma unroll
    for (int it = 0; it < 16; ++it) w[it] = *(const float4*)(wrow + it * 32);
  }
  const float bb = P.bhh[grow];            // used by kc==0 lanes
  const float* xgp = P.xg + grow;

  __shared__ float hs[4 * H_DIM];
  __shared__ float gred[32][4];
  __shared__ float cst[32];
  float thv = 0.f;
  if (tid < 32) {
    const int b = tid >> 3, cc = tid & 7;
    cst[tid] = P.c_init[b * H_DIM + col0 + cc];
    if (P.spk) thv = P.thr[col0 + cc];
  }

  for (int t = 0; t < P.nsteps; ++t) {
    // xg loads for this step (independent of h -> issue before poll)
    float xgv[4];
    if (kc == 0) {
#pragma unroll
      for (int b = 0; b < 4; ++b)
        xgv[b] = xgp[(size_t)(b * S_LEN + t) * P.xg_stride];
    }
    // wait for h(t)
    const float* hsrc;
    if (t == 0) {
      hsrc = P.h_init;
    } else {
      hsrc = P.hbuf + (t & 1) * (4 * H_DIM);
      if (tid < 64) {
        int cap = 0;
        while (true) {
          int v = __hip_atomic_load(&P.flags[tid], __ATOMIC_ACQUIRE,
                                    __HIP_MEMORY_SCOPE_AGENT);
          if (__all(v >= t)) break;
          __builtin_amdgcn_s_sleep(1);
          if (++cap > 4000000) break;   // safety: never hang the harness
        }
      }
    }
    __syncthreads();   // poll done; previous iter fully consumed hs/gred
    // stage h(t) into LDS (agent-scope loads bypass stale caches)
#pragma unroll
    for (int j = 0; j < 8; ++j)
      hs[j * 256 + tid] = __hip_atomic_load(hsrc + j * 256 + tid,
                                            __ATOMIC_RELAXED, __HIP_MEMORY_SCOPE_AGENT);
    __syncthreads();

    // matvec: row grow, 4 batches, k-chunk kc
    float a0 = 0.f, a1 = 0.f, a2 = 0.f, a3 = 0.f;
#pragma unroll
    for (int it = 0; it < 16; ++it) {
      const int k = it * 32 + kc * 4;
      const float4 wv = w[it];
      const float4 h0 = *(const float4*)&hs[0 * H_DIM + k];
      const float4 h1 = *(const float4*)&hs[1 * H_DIM + k];
      const float4 h2 = *(const float4*)&hs[2 * H_DIM + k];
      const float4 h3 = *(const float4*)&hs[3 * H_DIM + k];
      a0 += wv.x * h0.x + wv.y * h0.y + wv.z * h0.z + wv.w * h0.w;
      a1 += wv.x * h1.x + wv.y * h1.y + wv.z * h1.z + wv.w * h1.w;
      a2 += wv.x * h2.x + wv.y * h2.y + wv.z * h2.z + wv.w * h2.w;
      a3 += wv.x * h3.x + wv.y * h3.y + wv.z * h3.z + wv.w * h3.w;
    }
#pragma unroll
    for (int off = 1; off < 8; off <<= 1) {
      a0 += __shfl_xor(a0, off);
      a1 += __shfl_xor(a1, off);
      a2 += __shfl_xor(a2, off);
      a3 += __shfl_xor(a3, off);
    }
    if (kc == 0) {
      gred[lr][0] = a0 + xgv[0] + bb;
      gred[lr][1] = a1 + xgv[1] + bb;
      gred[lr][2] = a2 + xgv[2] + bb;
      gred[lr][3] = a3 + xgv[3] + bb;
    }
    __syncthreads();

    if (tid < 32) {
      const int b = tid & 3, cc = tid >> 2;
      const int col = col0 + cc;
      const float gi = gred[cc][b];
      const float gf = gred[8 + cc][b];
      const float gg = gred[16 + cc][b];
      const float go = gred[24 + cc][b];
      const float cold = cst[b * 8 + cc];
      const float cn = sigf(gf) * cold + sigf(gi) * tanhf(gg);
      const float hn = sigf(go) * tanhf(cn);
      cst[b * 8 + cc] = cn;
      __hip_atomic_store(P.hbuf + ((t + 1) & 1) * (4 * H_DIM) + b * H_DIM + col, hn,
                         __ATOMIC_RELAXED, __HIP_MEMORY_SCOPE_AGENT);
      if (P.spk)
        P.spk[(size_t)(b * S_LEN + t) * H_DIM + col] =
            (hn - P.thr[col]) > 0.f ? 1.f : 0.f;
      if (P.c_fin && t == P.nsteps - 1)
        P.c_fin[b * H_DIM + col] = cn;
    }
    __syncthreads();   // all h stores retired (vmcnt drained) before flag
    if (tid == 0)
      __hip_atomic_store(&P.flags[g], t + 1, __ATOMIC_RELEASE,
                         __HIP_MEMORY_SCOPE_AGENT);
  }
  (void)thv;
}

extern "C" void kernel_launch(void* const* d_in, const int* in_sizes, int n_in,
                              void* d_out, int out_size, void* d_ws, size_t ws_size,
                              hipStream_t stream) {
  (void)in_sizes; (void)n_in; (void)out_size; (void)ws_size;
  const int*   src       = (const int*)d_in[0];
  const int*   tgt       = (const int*)d_in[1];
  const float* emb_enc   = (const float*)d_in[2];
  const float* enc_alpha = (const float*)d_in[3];
  const float* enc_gamma = (const float*)d_in[4];
  const float* enc_beta  = (const float*)d_in[5];
  const float* enc_Wih   = (const float*)d_in[6];
  const float* enc_Whh   = (const float*)d_in[7];
  const float* enc_bih   = (const float*)d_in[8];
  const float* enc_bhh   = (const float*)d_in[9];
  const float* emb_dec   = (const float*)d_in[11];
  const float* dec_alpha = (const float*)d_in[12];
  const float* dec_gamma = (const float*)d_in[13];
  const float* dec_beta  = (const float*)d_in[14];
  const float* dec_Wih   = (const float*)d_in[15];
  const float* dec_Whh   = (const float*)d_in[16];
  const float* dec_bih   = (const float*)d_in[17];
  const float* dec_bhh   = (const float*)d_in[18];
  const float* dec_thr   = (const float*)d_in[19];
  const float* dec_fc_W  = (const float*)d_in[20];
  const float* dec_fc_b  = (const float*)d_in[21];
  const float* dyt_alpha = (const float*)d_in[22];
  const float* dyt_gamma = (const float*)d_in[23];
  const float* dyt_beta  = (const float*)d_in[24];
  const float* out_W     = (const float*)d_in[25];
  const float* out_b     = (const float*)d_in[26];
  float* out = (float*)d_out;

  float* ws     = (float*)d_ws;
  float* src_e  = ws;                       // [1024,512]
  float* dec_x0 = ws + 524288;              // [1024,512]
  float* dec_x1 = ws + 1048576;             // [1024,512]
  float* xg_enc = ws + 1572864;             // [1024,4096]
  float* xg_dec = ws + 5767168;             // [1024,2048]
  float* spk    = ws + 7864320;             // [1024,512]
  float* st     = ws + 8388608;             // control/state block
  float* zbuf   = st;                       // [2048] zeros (h0,c0)
  int*   flags  = (int*)(st + 2048);        // 4 x 64 flags (+pad to 4096)
  float* rings  = st + 4096;                // 4 x [2][2048]
  float* cfin   = st + 4096 + 16384;        // 2 x [2048]

  // zero zbuf + flags (4096 floats covers both)
  zero_kernel<<<4, 256, 0, stream>>>(st, 1024);
  embed_dyt<<<1024, 128, 0, stream>>>(src, emb_enc, enc_alpha, enc_gamma, enc_beta, src_e);
  embed_dyt<<<1024, 128, 0, stream>>>(tgt, emb_dec, dec_alpha, dec_gamma, dec_beta, dec_x0);

  // Encoder xg for both layers: W stacked [4096,512]
  gemm_nt<0><<<dim3(8, 32), 256, 0, stream>>>(src_e, enc_Wih, enc_bih, xg_enc, 4096, 512,
                                              nullptr, nullptr, nullptr, nullptr);

  // Encoder: both layers in one persistent dispatch (128 WGs)
  PhaseArgs E0, E1;
  E0.xg = xg_enc;        E0.Whh = enc_Whh;             E0.bhh = enc_bhh;
  E0.c_init = zbuf;      E0.h_init = zbuf;             E0.c_fin = cfin;
  E0.hbuf = rings;       E0.flags = flags;             E0.spk = nullptr;
  E0.thr = nullptr;      E0.xg_stride = 4096;          E0.nsteps = 256;
  E1 = E0;
  E1.xg = xg_enc + 2048; E1.Whh = enc_Whh + 1048576;   E1.bhh = enc_bhh + 2048;
  E1.c_fin = cfin + 2048;
  E1.hbuf = rings + 4096; E1.flags = flags + 64;
  slstm_persist<<<128, 256, 0, stream>>>(E0, E1);
  // final h(256) of layer l is rings[l] + 0 (parity 0); final c in cfin[l]

  const float* xin = dec_x0;
  float* xout = dec_x1;
  for (int l = 0; l < 2; ++l) {
    gemm_nt<0><<<dim3(8, 16), 256, 0, stream>>>(xin, dec_Wih + (size_t)l * 1048576,
                                                dec_bih + l * 2048, xg_dec, 2048, 512,
                                                nullptr, nullptr, nullptr, nullptr);
    PhaseArgs D;
    D.xg = xg_dec;                      D.Whh = dec_Whh + (size_t)l * 1048576;
    D.bhh = dec_bhh + l * 2048;
    D.c_init = cfin + l * 2048;         D.h_init = rings + l * 4096;  // enc ring parity 0
    D.c_fin = nullptr;
    D.hbuf = rings + (2 + l) * 4096;    D.flags = flags + (2 + l) * 64;
    D.spk = spk;                        D.thr = dec_thr + l * 512;
    D.xg_stride = 2048;                 D.nsteps = 256;
    slstm_persist<<<64, 256, 0, stream>>>(D, D);

    gemm_nt<1><<<dim3(8, 4), 256, 0, stream>>>(spk, dec_fc_W + (size_t)l * 262144,
                                               dec_fc_b + l * 512, xout, 512, 512,
                                               dyt_alpha + l, dyt_gamma + l * 512,
                                               dyt_beta + l * 512,
                                               (l > 0) ? xin : nullptr);
    const float* tmp = xin; xin = xout; xout = (float*)tmp;
  }

  gemm_nt<0><<<dim3(8, 250), 256, 0, stream>>>(xin, out_W, out_b, out, 32000, 512,
                                               nullptr, nullptr, nullptr, nullptr);
}